// Round 12
// baseline (222.060 us; speedup 1.0000x reference)
//
#include <hip/hip_runtime.h>
#include <hip/hip_bf16.h>
#include <math.h>
#include <stdint.h>

#define D_MODEL 1024
#define NHEADS  16
#define DHEAD   64
#define BATCH   2
#define SEQ     2048
#define ROWS    (BATCH*SEQ)   // 4096

#define NEG_BIG (-1e30f)
#define QSCALE  0.18033688011112042f   // 0.125 * log2(e): S*QSCALE -> exp2

typedef __bf16 bf16v8 __attribute__((ext_vector_type(8)));
typedef short  shortv8 __attribute__((ext_vector_type(8)));
typedef short  shortv4 __attribute__((ext_vector_type(4)));
typedef float  floatv4 __attribute__((ext_vector_type(4)));
typedef unsigned short ush;

__device__ __forceinline__ ush f2b(float f) {
  return __builtin_bit_cast(ush, (__bf16)f);
}

// async global->LDS, 16B per lane: HW writes lane i at ldsbase + i*16.
__device__ __forceinline__ void async16(ush* lds, const ush* g) {
  __builtin_amdgcn_global_load_lds(
      (const __attribute__((address_space(1))) void*)g,
      (__attribute__((address_space(3))) void*)lds, 16, 0, 0);
}

// ===========================================================================
// Fused prep: dtype-detect + cast x->bf16 + transpose both weights.
// Grid: [0,2048) cast | [2048,2816) wqkv transpose | [2816,3072) wproj.
// ===========================================================================
__global__ __launch_bounds__(256)
void prep(const uint32_t* __restrict__ x, ush* __restrict__ xb,
          const void* __restrict__ wqkv, ush* __restrict__ wqkvT,
          const void* __restrict__ wproj, ush* __restrict__ wprojT,
          int* __restrict__ flagp) {
  __shared__ int sflag;
  __shared__ __align__(16) ush tile[64][72];

  int bid = blockIdx.x;
  int t   = threadIdx.x;

  if (t < 64) {
    uint32_t e = (x[t] >> 7) & 0xFF;
    unsigned long long m = __ballot(e >= 96 && e <= 144);
    if (t == 0) sflag = (__popcll(m) >= 32) ? 1 : 0;
  }
  __syncthreads();
  int isbf = sflag;
  if (bid == 0 && t == 0) *flagp = isbf;

  if (bid < 2048) {
    size_t i = (size_t)bid * 256 + t;
    if (isbf) {
      ((shortv8*)xb)[i] = ((const shortv8*)x)[i];
    } else {
      const floatv4* p = ((const floatv4*)x) + i * 2;
      floatv4 a = p[0], b = p[1];
      shortv8 o;
#pragma unroll
      for (int j = 0; j < 4; ++j) { o[j] = (short)f2b(a[j]); o[4+j] = (short)f2b(b[j]); }
      ((shortv8*)xb)[i] = o;
    }
  } else {
    const void* W; ush* Wt; int N, b2;
    const int K = 1024;
    if (bid < 2816) { W = wqkv;  Wt = wqkvT;  N = 3072; b2 = bid - 2048; }
    else            { W = wproj; Wt = wprojT; N = 1024; b2 = bid - 2816; }
    int tiles_n = N >> 6;
    int tk = b2 / tiles_n;
    int tn = b2 % tiles_n;
    int r  = t >> 2;
    int c8 = (t & 3) * 8;

    if (isbf) {
      const ush* src = (const ush*)W + (size_t)(tk*64 + r) * N + tn*64;
#pragma unroll
      for (int c = 0; c < 2; ++c)
        *(shortv8*)&tile[r][c8 + c*32] = *(const shortv8*)&src[c8 + c*32];
    } else {
      const float* src = (const float*)W + (size_t)(tk*64 + r) * N + tn*64;
#pragma unroll
      for (int c = 0; c < 2; ++c) {
        const floatv4* p = (const floatv4*)&src[c8 + c*32];
        floatv4 a = p[0], b = p[1];
        shortv8 o;
#pragma unroll
        for (int j = 0; j < 4; ++j) { o[j] = (short)f2b(a[j]); o[4+j] = (short)f2b(b[j]); }
        *(shortv8*)&tile[r][c8 + c*32] = o;
      }
    }
    __syncthreads();
    ush* dst = Wt + (size_t)(tn*64 + r) * K + tk*64;
#pragma unroll
    for (int c = 0; c < 2; ++c) {
      int k8 = c8 + c*32;
      shortv8 v;
#pragma unroll
      for (int j = 0; j < 8; ++j) v[j] = (short)tile[k8 + j][r];
      *(shortv8*)&dst[k8] = v;
    }
  }
}

// ===========================================================================
// QKV GEMM v2.1: 256x256 tile, BK=64, 8 waves, 4 quadrant-phases per K-tile,
// counted vmcnt (never 0 in-loop), XOR-swizzled LDS via pre-swizzled global,
// XCD-chunked block swizzle (192 = 8 x 24).
// ===========================================================================
#define MFMA16(a,b,c) __builtin_amdgcn_mfma_f32_16x16x32_bf16(a,b,c,0,0,0)

__global__ __launch_bounds__(512, 2)
void gemm_qkv(const ush* __restrict__ A, const ush* __restrict__ Bt,
              ush* __restrict__ qb_, ush* __restrict__ kb_, ush* __restrict__ vb_) {
  __shared__ __align__(16) ush smem[65536];
  const int K = 1024;
  const int tiles_n = 12;           // 3072/256
  int raw = blockIdx.x;
  int bid = (raw & 7) * 24 + (raw >> 3);   // XCD-chunked, bijective (192=8x24)
  int m0 = (bid / tiles_n) * 256;
  int n0 = (bid % tiles_n) * 256;
  int t    = threadIdx.x;
  int lane = t & 63;
  int w    = t >> 6;
  int wr   = w >> 2;
  int wc   = w & 3;
  int lr   = lane & 15;
  int quad = lane >> 4;
  int r8   = lane >> 3;
  int s8   = lane & 7;
  int g8   = s8 ^ r8;

  int aeo = 2*w + (w>>2)*8;
  int alo = aeo + 8;
  int beo = (w>>1)*8 + (w&1)*2;
  int blo = beo + 4;

  const ush* gAe0 = A  + (size_t)(m0 + aeo*8     + r8)*K + g8*8;
  const ush* gAe1 = gAe0 + (size_t)8*K;
  const ush* gAl0 = A  + (size_t)(m0 + alo*8     + r8)*K + g8*8;
  const ush* gAl1 = gAl0 + (size_t)8*K;
  const ush* gBe0 = Bt + (size_t)(n0 + beo*8     + r8)*K + g8*8;
  const ush* gBe1 = gBe0 + (size_t)8*K;
  const ush* gBl0 = Bt + (size_t)(n0 + blo*8     + r8)*K + g8*8;
  const ush* gBl1 = gBl0 + (size_t)8*K;

  int lAe0 = aeo*512,         lAe1 = lAe0 + 512;
  int lAl0 = alo*512,         lAl1 = lAl0 + 512;
  int lBe0 = 32768 + beo*512, lBe1 = lBe0 + 512;
  int lBl0 = 32768 + blo*512, lBl1 = lBl0 + 512;

  floatv4 acc[4][8] = {};
  bf16v8 af[4][2];
  bf16v8 bf[4][2];

  int sk0 = ((quad    ) ^ (lr & 7)) * 8;
  int sk1 = ((quad + 4) ^ (lr & 7)) * 8;

  async16(&smem[lAe0], gAe0); async16(&smem[lAe1], gAe1);
  async16(&smem[lBe0], gBe0); async16(&smem[lBe1], gBe1);
  async16(&smem[lBl0], gBl0); async16(&smem[lBl1], gBl1);
  async16(&smem[lAl0], gAl0); async16(&smem[lAl1], gAl1);

  for (int kt = 0; kt < 16; ++kt) {
    int cur = kt & 1, nx = cur ^ 1;
    int kn  = (kt + 1 < 16) ? (kt + 1) : 15;
    int ko  = kn * 64;
    int nb  = nx * 16384;

    const ush* Ab = &smem[cur*16384 + (wr*128 + lr)*64];
    const ush* Bb = &smem[32768 + cur*16384 + (wc*64 + lr)*64];

    asm volatile("s_waitcnt vmcnt(4)" ::: "memory");
    __builtin_amdgcn_s_barrier();

    // P0: (mh0, nh0)
#pragma unroll
    for (int mi = 0; mi < 4; ++mi) {
      af[mi][0] = *(const bf16v8*)&Ab[mi*1024 + sk0];
      af[mi][1] = *(const bf16v8*)&Ab[mi*1024 + sk1];
    }
#pragma unroll
    for (int ni = 0; ni < 2; ++ni) {
      bf[ni][0] = *(const bf16v8*)&Bb[ni*1024 + sk0];
      bf[ni][1] = *(const bf16v8*)&Bb[ni*1024 + sk1];
    }
    async16(&smem[nb + lAe0], gAe0 + ko); async16(&smem[nb + lAe1], gAe1 + ko);
    __builtin_amdgcn_s_setprio(1);
#pragma unroll
    for (int ni = 0; ni < 2; ++ni)
#pragma unroll
      for (int mi = 0; mi < 4; ++mi)
#pragma unroll
        for (int ks = 0; ks < 2; ++ks)
          acc[ni][mi] = MFMA16(bf[ni][ks], af[mi][ks], acc[ni][mi]);
    __builtin_amdgcn_s_setprio(0);

    asm volatile("s_waitcnt vmcnt(4)" ::: "memory");
    __builtin_amdgcn_s_barrier();

    // P1: (mh0, nh1)
#pragma unroll
    for (int ni = 0; ni < 2; ++ni) {
      bf[2+ni][0] = *(const bf16v8*)&Bb[(2+ni)*1024 + sk0];
      bf[2+ni][1] = *(const bf16v8*)&Bb[(2+ni)*1024 + sk1];
    }
    async16(&smem[nb + lBe0], gBe0 + ko); async16(&smem[nb + lBe1], gBe1 + ko);
    __builtin_amdgcn_s_setprio(1);
#pragma unroll
    for (int ni = 0; ni < 2; ++ni)
#pragma unroll
      for (int mi = 0; mi < 4; ++mi)
#pragma unroll
        for (int ks = 0; ks < 2; ++ks)
          acc[2+ni][mi] = MFMA16(bf[2+ni][ks], af[mi][ks], acc[2+ni][mi]);
    __builtin_amdgcn_s_setprio(0);

    asm volatile("s_waitcnt vmcnt(4)" ::: "memory");
    __builtin_amdgcn_s_barrier();

    // P2: (mh1, nh0)
#pragma unroll
    for (int mi = 0; mi < 4; ++mi) {
      af[mi][0] = *(const bf16v8*)&Ab[4096 + mi*1024 + sk0];
      af[mi][1] = *(const bf16v8*)&Ab[4096 + mi*1024 + sk1];
    }
    async16(&smem[nb + lBl0], gBl0 + ko); async16(&smem[nb + lBl1], gBl1 + ko);
    __builtin_amdgcn_s_setprio(1);
#pragma unroll
    for (int ni = 0; ni < 2; ++ni)
#pragma unroll
      for (int mi = 0; mi < 4; ++mi)
#pragma unroll
        for (int ks = 0; ks < 2; ++ks)
          acc[ni][4+mi] = MFMA16(bf[ni][ks], af[mi][ks], acc[ni][4+mi]);
    __builtin_amdgcn_s_setprio(0);

    __builtin_amdgcn_s_barrier();

    // P3: (mh1, nh1)
    async16(&smem[nb + lAl0], gAl0 + ko); async16(&smem[nb + lAl1], gAl1 + ko);
    __builtin_amdgcn_s_setprio(1);
#pragma unroll
    for (int ni = 0; ni < 2; ++ni)
#pragma unroll
      for (int mi = 0; mi < 4; ++mi)
#pragma unroll
        for (int ks = 0; ks < 2; ++ks)
          acc[2+ni][4+mi] = MFMA16(bf[2+ni][ks], af[mi][ks], acc[2+ni][4+mi]);
    __builtin_amdgcn_s_setprio(0);
  }

  asm volatile("s_waitcnt vmcnt(0)" ::: "memory");
  __builtin_amdgcn_s_barrier();

  int s   = n0 >> 10;
  int h   = ((n0 & 1023) + wc*64) >> 6;
  int b   = (m0 + wr*128) >> 11;
  int bh  = b*16 + h;
  int ttw = (m0 + wr*128) & 2047;

  if (s < 2) {
    ush* dst = (s == 0) ? qb_ : kb_;
    float sc = (s == 0) ? QSCALE : 1.0f;
#pragma unroll
    for (int ni = 0; ni < 4; ++ni) {
      int d4 = ni*16 + quad*4;
#pragma unroll
      for (int mi = 0; mi < 8; ++mi) {
        int tt = ttw + mi*16 + lr;
        shortv4 v4;
#pragma unroll
        for (int r = 0; r < 4; ++r) v4[r] = (short)f2b(acc[ni][mi][r] * sc);
        *(shortv4*)&dst[((size_t)bh*SEQ + tt)*64 + d4] = v4;
      }
    }
  } else {
    ush* L = &smem[w*4096];
#pragma unroll
    for (int th = 0; th < 2; ++th) {
      int tw = ttw + th*64;
#pragma unroll
      for (int ni = 0; ni < 4; ++ni) {
#pragma unroll
        for (int r = 0; r < 4; ++r) {
          int dl = ni*16 + quad*4 + r;
          shortv4 p4;
#pragma unroll
          for (int j = 0; j < 4; ++j) p4[j] = (short)f2b(acc[ni][th*4 + j][r]);
          int slot = (lr >> 1) ^ (dl & 7);
          *(shortv4*)&L[dl*64 + slot*8 + (lr & 1)*4] = p4;
        }
      }
#pragma unroll
      for (int p = 0; p < 8; ++p) {
        int dl = p*8 + (lane >> 3);
        int c8 = lane & 7;
        int slot = c8 ^ (dl & 7);
        shortv8 v = *(shortv8*)&L[dl*64 + slot*8];
        *(shortv8*)&vb_[((size_t)bh*64 + dl)*SEQ + tw + c8*8] = v;
      }
    }
  }
}

// ---------------------------------------------------------------------------
// Proj GEMM, 64x128 tile. XCD-chunked swizzle: 512 blocks, 64/XCD contiguous.
// ---------------------------------------------------------------------------
__global__ __launch_bounds__(256, 4)
void gemm_bt(const ush* __restrict__ A, const ush* __restrict__ Bt,
             void* __restrict__ Cp, const int* __restrict__ flag,
             int ldc, int tiles_n) {
  __shared__ __align__(16) ush smem[12288];
  const int K = 1024;
  int raw = blockIdx.x;
  int bid = ((raw & 7) << 6) | (raw >> 3);   // bijective for 512 blocks
  int m0 = (bid / tiles_n) * 64;
  int n0 = (bid % tiles_n) * 128;
  int t    = threadIdx.x;
  int lane = t & 63;
  int w    = t >> 6;
  int wm   = (w >> 1) * 32;
  int wn   = (w & 1) * 64;
  int lr   = lane & 15;
  int quad = lane >> 4;
  floatv4 acc[4][2] = {};
  int r16 = lane >> 2;
  int g4  = (lane & 3) ^ (r16 & 3);
  const ush* gA0 = A  + (size_t)(m0 + 16*w + r16)*K + g4*8;
  const ush* gB0 = Bt + (size_t)(n0 + 32*w + r16)*K + g4*8;
  const ush* gB1 = gB0 + (size_t)16*K;
  int fs = (quad ^ (lr & 3)) * 8;

  async16(&smem[(16*w)*32], gA0);
  async16(&smem[4096 + (32*w)*32], gB0);
  async16(&smem[4096 + (32*w+16)*32], gB1);

  for (int kk = 0; kk < K; kk += 32) {
    int cur = (kk >> 5) & 1;
    __syncthreads();
    if (kk + 32 < K) {
      int nx = cur ^ 1;
      async16(&smem[nx*2048 + (16*w)*32], gA0 + kk + 32);
      async16(&smem[4096 + nx*4096 + (32*w)*32], gB0 + kk + 32);
      async16(&smem[4096 + nx*4096 + (32*w+16)*32], gB1 + kk + 32);
    }
    bf16v8 af[2], bfr[4];
#pragma unroll
    for (int j = 0; j < 2; ++j)
      af[j] = *(bf16v8*)&smem[cur*2048 + (wm + j*16 + lr)*32 + fs];
#pragma unroll
    for (int i = 0; i < 4; ++i)
      bfr[i] = *(bf16v8*)&smem[4096 + cur*4096 + (wn + i*16 + lr)*32 + fs];
#pragma unroll
    for (int i = 0; i < 4; ++i)
#pragma unroll
      for (int j = 0; j < 2; ++j)
        acc[i][j] = __builtin_amdgcn_mfma_f32_16x16x32_bf16(bfr[i], af[j],
                                                            acc[i][j], 0, 0, 0);
  }

  int f32out = (flag != nullptr) && (*flag == 0);
  if (f32out) {
    float* Cf = (float*)Cp;
#pragma unroll
    for (int i = 0; i < 4; ++i) {
      int nb = n0 + wn + i*16 + quad*4;
#pragma unroll
      for (int j = 0; j < 2; ++j) {
        int row = m0 + wm + j*16 + lr;
        *(floatv4*)&Cf[(size_t)row*ldc + nb] = acc[i][j];
      }
    }
  } else {
    __hip_bfloat16* Cb = (__hip_bfloat16*)Cp;
#pragma unroll
    for (int i = 0; i < 4; ++i) {
      int nb = n0 + wn + i*16 + quad*4;
#pragma unroll
      for (int j = 0; j < 2; ++j) {
        int row = m0 + wm + j*16 + lr;
        shortv4 v4;
#pragma unroll
        for (int r = 0; r < 4; ++r) v4[r] = (short)f2b(acc[i][j][r]);
        *(shortv4*)&((ush*)Cb)[(size_t)row*ldc + nb] = v4;
      }
    }
  }
}

// ===========================================================================
// Flash attention v13: v12 skeleton (one 128-row q-block, 8 strip-waves,
// balance, XCD swizzle) MINUS the V LDS pipeline. V per head is 256 KB
// (L2-resident; 2 co-resident heads/CU -> live V tiles ~16 KB, L1-friendly),
// so V-staging was pure overhead (m169 pattern: +26%). V MFMA B-fragments
// are read STRAIGHT from global -- the XOR staging and XOR read cancel:
//   vf0 = vh[(16c+lr)*SEQ + tk*64 + quad*8], vf1 = ... + (quad+4)*8.
// All 8 V loads are issued at the top of the live block so QK+softmax
// (~400 cyc) covers L1/L2 latency. K staging/barriers/Ps unchanged.
// LDS 51200 -> 34 KB.
// ===========================================================================
#define PSTR 72

__device__ __forceinline__ void softpack(const floatv4* s, int qw, int kb0,
                                         bool diag, ush* PsW, int quad, int lr) {
  if (diag) {
#pragma unroll
    for (int r = 0; r < 4; ++r) {
      int qv = qw + quad*4 + r;
      shortv4 p4;
#pragma unroll
      for (int j = 0; j < 4; ++j) {
        float z = (kb0 + 16*j + lr > qv) ? NEG_BIG : s[j][r];
        p4[j] = (short)f2b(__builtin_amdgcn_exp2f(z));
      }
      *(shortv4*)&PsW[(quad*4 + r)*PSTR + lr*4] = p4;
    }
  } else {
#pragma unroll
    for (int r = 0; r < 4; ++r) {
      shortv4 p4;
#pragma unroll
      for (int j = 0; j < 4; ++j)
        p4[j] = (short)f2b(__builtin_amdgcn_exp2f(s[j][r]));
      *(shortv4*)&PsW[(quad*4 + r)*PSTR + lr*4] = p4;
    }
  }
}

__global__ __launch_bounds__(512, 4)
void attn_fwd(const ush* __restrict__ qb_, const ush* __restrict__ kb_,
              const ush* __restrict__ vb_, __hip_bfloat16* __restrict__ ctx) {
  __shared__ __align__(16) ush Ks[2][64*64];
  __shared__ __align__(16) ush Ps[8][16*PSTR];

  int raw = blockIdx.x;
  int bid = ((raw & 7) << 6) | (raw >> 3);   // XCD-chunked (512 = 8 x 64)
  int g   = (bid & 15) ^ (((bid >> 5) & 1) ? 15 : 0);
  int bh  = bid >> 4;              // 0..31
  int h   = bh & 15;
  int b   = bh >> 4;

  int t = threadIdx.x, w8 = t >> 6, lane = t & 63, lr = lane & 15, quad = lane >> 4;

  const ush* qh = qb_ + (size_t)bh * SEQ * 64;
  const ush* kh = kb_ + (size_t)bh * SEQ * 64;
  const ush* vh = vb_ + (size_t)bh * 64 * SEQ;

  int qw     = g*128 + w8*16;
  int myLast = 2*g + (w8 >> 2);
  int wj     = w8 & 3;

  const ush* qp = qh + (size_t)(qw + lr)*64;
  bf16v8 qf0 = *(const bf16v8*)&qp[quad*8];
  bf16v8 qf1 = *(const bf16v8*)&qp[32 + quad*8];

  floatv4 acc[4] = {}, acl = {};

  bf16v8 ones;
#pragma unroll
  for (int j = 0; j < 8; ++j) ones[j] = (__bf16)1.0f;

  int r8 = lane >> 3;
  int s8 = lane & 7;
  int g8 = s8 ^ r8;
  const ush* kg = kh + (size_t)(8*w8 + r8)*64 + g8*8;
  int lo = (8*w8)*64;

  int sl0 = quad ^ (lr & 7);
  int sl1 = (quad + 4) ^ (lr & 7);

  int ntiles = 2*g + 2;

  async16(&Ks[0][lo], kg);

  for (int tk = 0; tk < ntiles; ++tk) {
    int cur = tk & 1;
    __syncthreads();
    if (tk + 1 < ntiles) {
      int nx = cur ^ 1;
      async16(&Ks[nx][lo], kg + (size_t)(tk + 1) * 64 * 64);
    }

    bool live = (tk <= myLast);
    if (live) {
      int kb0 = tk * 64;
      bool diag = (tk == myLast);

      // ---- V fragments straight from global (L1/L2), issued EARLY so the
      //      QK MFMA + softmax chain below covers the load latency.
      bf16v8 vf[4][2];
      const ush* vt0 = vh + (size_t)kb0;
#pragma unroll
      for (int c = 0; c < 4; ++c) {
        const ush* vrow = vt0 + (size_t)(16*c + lr)*SEQ;
        vf[c][0] = *(const bf16v8*)&vrow[quad*8];
        vf[c][1] = *(const bf16v8*)&vrow[(quad + 4)*8];
      }

      floatv4 s[4] = {};
      __builtin_amdgcn_s_setprio(1);
#pragma unroll
      for (int j = 0; j < 4; ++j) {
        if (!diag || j <= wj) {
          int row = 16*j + lr;
          bf16v8 kf0 = *(bf16v8*)&Ks[cur][row*64 + sl0*8];
          bf16v8 kf1 = *(bf16v8*)&Ks[cur][row*64 + sl1*8];
          s[j] = MFMA16(qf0, kf0, s[j]);
          s[j] = MFMA16(qf1, kf1, s[j]);
        }
      }
      __builtin_amdgcn_s_setprio(0);

      softpack(s, qw, kb0, diag, &Ps[w8][0], quad, lr);

      bf16v8 pf0 = *(bf16v8*)&Ps[w8][lr*PSTR + quad*8];
      bf16v8 pf1 = *(bf16v8*)&Ps[w8][lr*PSTR + 32 + quad*8];

      __builtin_amdgcn_s_setprio(1);
      acl = MFMA16(pf0, ones, acl);
      acl = MFMA16(pf1, ones, acl);

#pragma unroll
      for (int c = 0; c < 4; ++c) {
        acc[c] = MFMA16(pf0, vf[c][0], acc[c]);
        acc[c] = MFMA16(pf1, vf[c][1], acc[c]);
      }
      __builtin_amdgcn_s_setprio(0);
    }
  }

#pragma unroll
  for (int r = 0; r < 4; ++r) {
    float inv = 1.0f / fmaxf(acl[r], 1e-30f);
    size_t o = (size_t)(b*SEQ + qw + quad*4 + r) * D_MODEL + h*64;
#pragma unroll
    for (int c = 0; c < 4; ++c)
      ctx[o + c*16 + lr] = __float2bfloat16(acc[c][r] * inv);
  }
}

// ---------------------------------------------------------------------------
extern "C" void kernel_launch(void* const* d_in, const int* in_sizes, int n_in,
                              void* d_out, int out_size, void* d_ws, size_t ws_size,
                              hipStream_t stream) {
  const void* x      = d_in[0];
  const void* w_qkv  = d_in[1];
  const void* w_proj = d_in[2];

  int* flag   = (int*)d_ws;
  ush* xb     = (ush*)d_ws + 8;
  ush* wqkvT  = xb     + (size_t)ROWS * D_MODEL;
  ush* wprojT = wqkvT  + (size_t)3072 * 1024;
  ush* qbuf   = wprojT + (size_t)1024 * 1024;
  ush* kbuf   = qbuf   + (size_t)32 * SEQ * 64;
  ush* vbuf   = kbuf   + (size_t)32 * SEQ * 64;
  ush* ctx    = xb;   // alias: xb dead after gemm_qkv, before attn writes ctx

  prep<<<3072, 256, 0, stream>>>((const uint32_t*)x, xb,
                                 w_qkv, wqkvT, w_proj, wprojT, flag);

  gemm_qkv<<<192, 512, 0, stream>>>(xb, wqkvT, qbuf, kbuf, vbuf);

  attn_fwd<<<BATCH * NHEADS * 16, 512, 0, stream>>>(
      qbuf, kbuf, vbuf, (__hip_bfloat16*)ctx);

  gemm_bt<<<(ROWS/64)*(1024/128), 256, 0, stream>>>(
      ctx, wprojT, d_out, flag, 1024, 1024/128);
}

// Round 13
// 171.976 us; speedup vs baseline: 1.2912x; 1.2912x over previous
//
#include <hip/hip_runtime.h>
#include <hip/hip_bf16.h>
#include <math.h>
#include <stdint.h>

#define D_MODEL 1024
#define NHEADS  16
#define DHEAD   64
#define BATCH   2
#define SEQ     2048
#define ROWS    (BATCH*SEQ)   // 4096

#define NEG_BIG (-1e30f)
#define QSCALE  0.18033688011112042f   // 0.125 * log2(e): S*QSCALE -> exp2

typedef __bf16 bf16v8 __attribute__((ext_vector_type(8)));
typedef short  shortv8 __attribute__((ext_vector_type(8)));
typedef short  shortv4 __attribute__((ext_vector_type(4)));
typedef float  floatv4 __attribute__((ext_vector_type(4)));
typedef unsigned short ush;

__device__ __forceinline__ ush f2b(float f) {
  return __builtin_bit_cast(ush, (__bf16)f);
}

// async global->LDS, 16B per lane: HW writes lane i at ldsbase + i*16.
__device__ __forceinline__ void async16(ush* lds, const ush* g) {
  __builtin_amdgcn_global_load_lds(
      (const __attribute__((address_space(1))) void*)g,
      (__attribute__((address_space(3))) void*)lds, 16, 0, 0);
}

// ===========================================================================
// Fused prep: dtype-detect + cast x->bf16 + transpose both weights.
// ===========================================================================
__global__ __launch_bounds__(256)
void prep(const uint32_t* __restrict__ x, ush* __restrict__ xb,
          const void* __restrict__ wqkv, ush* __restrict__ wqkvT,
          const void* __restrict__ wproj, ush* __restrict__ wprojT,
          int* __restrict__ flagp) {
  __shared__ int sflag;
  __shared__ __align__(16) ush tile[64][72];

  int bid = blockIdx.x;
  int t   = threadIdx.x;

  if (t < 64) {
    uint32_t e = (x[t] >> 7) & 0xFF;
    unsigned long long m = __ballot(e >= 96 && e <= 144);
    if (t == 0) sflag = (__popcll(m) >= 32) ? 1 : 0;
  }
  __syncthreads();
  int isbf = sflag;
  if (bid == 0 && t == 0) *flagp = isbf;

  if (bid < 2048) {
    size_t i = (size_t)bid * 256 + t;
    if (isbf) {
      ((shortv8*)xb)[i] = ((const shortv8*)x)[i];
    } else {
      const floatv4* p = ((const floatv4*)x) + i * 2;
      floatv4 a = p[0], b = p[1];
      shortv8 o;
#pragma unroll
      for (int j = 0; j < 4; ++j) { o[j] = (short)f2b(a[j]); o[4+j] = (short)f2b(b[j]); }
      ((shortv8*)xb)[i] = o;
    }
  } else {
    const void* W; ush* Wt; int N, b2;
    const int K = 1024;
    if (bid < 2816) { W = wqkv;  Wt = wqkvT;  N = 3072; b2 = bid - 2048; }
    else            { W = wproj; Wt = wprojT; N = 1024; b2 = bid - 2816; }
    int tiles_n = N >> 6;
    int tk = b2 / tiles_n;
    int tn = b2 % tiles_n;
    int r  = t >> 2;
    int c8 = (t & 3) * 8;

    if (isbf) {
      const ush* src = (const ush*)W + (size_t)(tk*64 + r) * N + tn*64;
#pragma unroll
      for (int c = 0; c < 2; ++c)
        *(shortv8*)&tile[r][c8 + c*32] = *(const shortv8*)&src[c8 + c*32];
    } else {
      const float* src = (const float*)W + (size_t)(tk*64 + r) * N + tn*64;
#pragma unroll
      for (int c = 0; c < 2; ++c) {
        const floatv4* p = (const floatv4*)&src[c8 + c*32];
        floatv4 a = p[0], b = p[1];
        shortv8 o;
#pragma unroll
        for (int j = 0; j < 4; ++j) { o[j] = (short)f2b(a[j]); o[4+j] = (short)f2b(b[j]); }
        *(shortv8*)&tile[r][c8 + c*32] = o;
      }
    }
    __syncthreads();
    ush* dst = Wt + (size_t)(tn*64 + r) * K + tk*64;
#pragma unroll
    for (int c = 0; c < 2; ++c) {
      int k8 = c8 + c*32;
      shortv8 v;
#pragma unroll
      for (int j = 0; j < 8; ++j) v[j] = (short)tile[k8 + j][r];
      *(shortv8*)&dst[k8] = v;
    }
  }
}

// ===========================================================================
// QKV GEMM v2.1: 256x256 tile, BK=64, 8 waves, 4 quadrant-phases per K-tile,
// counted vmcnt, XOR-swizzled LDS, XCD-chunked block swizzle (192 = 8 x 24).
// ===========================================================================
#define MFMA16(a,b,c) __builtin_amdgcn_mfma_f32_16x16x32_bf16(a,b,c,0,0,0)

__global__ __launch_bounds__(512, 2)
void gemm_qkv(const ush* __restrict__ A, const ush* __restrict__ Bt,
              ush* __restrict__ qb_, ush* __restrict__ kb_, ush* __restrict__ vb_) {
  __shared__ __align__(16) ush smem[65536];
  const int K = 1024;
  const int tiles_n = 12;           // 3072/256
  int raw = blockIdx.x;
  int bid = (raw & 7) * 24 + (raw >> 3);   // XCD-chunked, bijective (192=8x24)
  int m0 = (bid / tiles_n) * 256;
  int n0 = (bid % tiles_n) * 256;
  int t    = threadIdx.x;
  int lane = t & 63;
  int w    = t >> 6;
  int wr   = w >> 2;
  int wc   = w & 3;
  int lr   = lane & 15;
  int quad = lane >> 4;
  int r8   = lane >> 3;
  int s8   = lane & 7;
  int g8   = s8 ^ r8;

  int aeo = 2*w + (w>>2)*8;
  int alo = aeo + 8;
  int beo = (w>>1)*8 + (w&1)*2;
  int blo = beo + 4;

  const ush* gAe0 = A  + (size_t)(m0 + aeo*8     + r8)*K + g8*8;
  const ush* gAe1 = gAe0 + (size_t)8*K;
  const ush* gAl0 = A  + (size_t)(m0 + alo*8     + r8)*K + g8*8;
  const ush* gAl1 = gAl0 + (size_t)8*K;
  const ush* gBe0 = Bt + (size_t)(n0 + beo*8     + r8)*K + g8*8;
  const ush* gBe1 = gBe0 + (size_t)8*K;
  const ush* gBl0 = Bt + (size_t)(n0 + blo*8     + r8)*K + g8*8;
  const ush* gBl1 = gBl0 + (size_t)8*K;

  int lAe0 = aeo*512,         lAe1 = lAe0 + 512;
  int lAl0 = alo*512,         lAl1 = lAl0 + 512;
  int lBe0 = 32768 + beo*512, lBe1 = lBe0 + 512;
  int lBl0 = 32768 + blo*512, lBl1 = lBl0 + 512;

  floatv4 acc[4][8] = {};
  bf16v8 af[4][2];
  bf16v8 bf[4][2];

  int sk0 = ((quad    ) ^ (lr & 7)) * 8;
  int sk1 = ((quad + 4) ^ (lr & 7)) * 8;

  async16(&smem[lAe0], gAe0); async16(&smem[lAe1], gAe1);
  async16(&smem[lBe0], gBe0); async16(&smem[lBe1], gBe1);
  async16(&smem[lBl0], gBl0); async16(&smem[lBl1], gBl1);
  async16(&smem[lAl0], gAl0); async16(&smem[lAl1], gAl1);

  for (int kt = 0; kt < 16; ++kt) {
    int cur = kt & 1, nx = cur ^ 1;
    int kn  = (kt + 1 < 16) ? (kt + 1) : 15;
    int ko  = kn * 64;
    int nb  = nx * 16384;

    const ush* Ab = &smem[cur*16384 + (wr*128 + lr)*64];
    const ush* Bb = &smem[32768 + cur*16384 + (wc*64 + lr)*64];

    asm volatile("s_waitcnt vmcnt(4)" ::: "memory");
    __builtin_amdgcn_s_barrier();

    // P0: (mh0, nh0)
#pragma unroll
    for (int mi = 0; mi < 4; ++mi) {
      af[mi][0] = *(const bf16v8*)&Ab[mi*1024 + sk0];
      af[mi][1] = *(const bf16v8*)&Ab[mi*1024 + sk1];
    }
#pragma unroll
    for (int ni = 0; ni < 2; ++ni) {
      bf[ni][0] = *(const bf16v8*)&Bb[ni*1024 + sk0];
      bf[ni][1] = *(const bf16v8*)&Bb[ni*1024 + sk1];
    }
    async16(&smem[nb + lAe0], gAe0 + ko); async16(&smem[nb + lAe1], gAe1 + ko);
    __builtin_amdgcn_s_setprio(1);
#pragma unroll
    for (int ni = 0; ni < 2; ++ni)
#pragma unroll
      for (int mi = 0; mi < 4; ++mi)
#pragma unroll
        for (int ks = 0; ks < 2; ++ks)
          acc[ni][mi] = MFMA16(bf[ni][ks], af[mi][ks], acc[ni][mi]);
    __builtin_amdgcn_s_setprio(0);

    asm volatile("s_waitcnt vmcnt(4)" ::: "memory");
    __builtin_amdgcn_s_barrier();

    // P1: (mh0, nh1)
#pragma unroll
    for (int ni = 0; ni < 2; ++ni) {
      bf[2+ni][0] = *(const bf16v8*)&Bb[(2+ni)*1024 + sk0];
      bf[2+ni][1] = *(const bf16v8*)&Bb[(2+ni)*1024 + sk1];
    }
    async16(&smem[nb + lBe0], gBe0 + ko); async16(&smem[nb + lBe1], gBe1 + ko);
    __builtin_amdgcn_s_setprio(1);
#pragma unroll
    for (int ni = 0; ni < 2; ++ni)
#pragma unroll
      for (int mi = 0; mi < 4; ++mi)
#pragma unroll
        for (int ks = 0; ks < 2; ++ks)
          acc[2+ni][mi] = MFMA16(bf[2+ni][ks], af[mi][ks], acc[2+ni][mi]);
    __builtin_amdgcn_s_setprio(0);

    asm volatile("s_waitcnt vmcnt(4)" ::: "memory");
    __builtin_amdgcn_s_barrier();

    // P2: (mh1, nh0)
#pragma unroll
    for (int mi = 0; mi < 4; ++mi) {
      af[mi][0] = *(const bf16v8*)&Ab[4096 + mi*1024 + sk0];
      af[mi][1] = *(const bf16v8*)&Ab[4096 + mi*1024 + sk1];
    }
    async16(&smem[nb + lBl0], gBl0 + ko); async16(&smem[nb + lBl1], gBl1 + ko);
    __builtin_amdgcn_s_setprio(1);
#pragma unroll
    for (int ni = 0; ni < 2; ++ni)
#pragma unroll
      for (int mi = 0; mi < 4; ++mi)
#pragma unroll
        for (int ks = 0; ks < 2; ++ks)
          acc[ni][4+mi] = MFMA16(bf[ni][ks], af[mi][ks], acc[ni][4+mi]);
    __builtin_amdgcn_s_setprio(0);

    __builtin_amdgcn_s_barrier();

    // P3: (mh1, nh1)
    async16(&smem[nb + lAl0], gAl0 + ko); async16(&smem[nb + lAl1], gAl1 + ko);
    __builtin_amdgcn_s_setprio(1);
#pragma unroll
    for (int ni = 0; ni < 2; ++ni)
#pragma unroll
      for (int mi = 0; mi < 4; ++mi)
#pragma unroll
        for (int ks = 0; ks < 2; ++ks)
          acc[2+ni][4+mi] = MFMA16(bf[2+ni][ks], af[mi][ks], acc[2+ni][4+mi]);
    __builtin_amdgcn_s_setprio(0);
  }

  asm volatile("s_waitcnt vmcnt(0)" ::: "memory");
  __builtin_amdgcn_s_barrier();

  int s   = n0 >> 10;
  int h   = ((n0 & 1023) + wc*64) >> 6;
  int b   = (m0 + wr*128) >> 11;
  int bh  = b*16 + h;
  int ttw = (m0 + wr*128) & 2047;

  if (s < 2) {
    ush* dst = (s == 0) ? qb_ : kb_;
    float sc = (s == 0) ? QSCALE : 1.0f;
#pragma unroll
    for (int ni = 0; ni < 4; ++ni) {
      int d4 = ni*16 + quad*4;
#pragma unroll
      for (int mi = 0; mi < 8; ++mi) {
        int tt = ttw + mi*16 + lr;
        shortv4 v4;
#pragma unroll
        for (int r = 0; r < 4; ++r) v4[r] = (short)f2b(acc[ni][mi][r] * sc);
        *(shortv4*)&dst[((size_t)bh*SEQ + tt)*64 + d4] = v4;
      }
    }
  } else {
    ush* L = &smem[w*4096];
#pragma unroll
    for (int th = 0; th < 2; ++th) {
      int tw = ttw + th*64;
#pragma unroll
      for (int ni = 0; ni < 4; ++ni) {
#pragma unroll
        for (int r = 0; r < 4; ++r) {
          int dl = ni*16 + quad*4 + r;
          shortv4 p4;
#pragma unroll
          for (int j = 0; j < 4; ++j) p4[j] = (short)f2b(acc[ni][th*4 + j][r]);
          int slot = (lr >> 1) ^ (dl & 7);
          *(shortv4*)&L[dl*64 + slot*8 + (lr & 1)*4] = p4;
        }
      }
#pragma unroll
      for (int p = 0; p < 8; ++p) {
        int dl = p*8 + (lane >> 3);
        int c8 = lane & 7;
        int slot = c8 ^ (dl & 7);
        shortv8 v = *(shortv8*)&L[dl*64 + slot*8];
        *(shortv8*)&vb_[((size_t)bh*64 + dl)*SEQ + tw + c8*8] = v;
      }
    }
  }
}

// ---------------------------------------------------------------------------
// Proj GEMM, 64x128 tile. XCD-chunked swizzle.
// ---------------------------------------------------------------------------
__global__ __launch_bounds__(256, 4)
void gemm_bt(const ush* __restrict__ A, const ush* __restrict__ Bt,
             void* __restrict__ Cp, const int* __restrict__ flag,
             int ldc, int tiles_n) {
  __shared__ __align__(16) ush smem[12288];
  const int K = 1024;
  int raw = blockIdx.x;
  int bid = ((raw & 7) << 6) | (raw >> 3);   // bijective for 512 blocks
  int m0 = (bid / tiles_n) * 64;
  int n0 = (bid % tiles_n) * 128;
  int t    = threadIdx.x;
  int lane = t & 63;
  int w    = t >> 6;
  int wm   = (w >> 1) * 32;
  int wn   = (w & 1) * 64;
  int lr   = lane & 15;
  int quad = lane >> 4;
  floatv4 acc[4][2] = {};
  int r16 = lane >> 2;
  int g4  = (lane & 3) ^ (r16 & 3);
  const ush* gA0 = A  + (size_t)(m0 + 16*w + r16)*K + g4*8;
  const ush* gB0 = Bt + (size_t)(n0 + 32*w + r16)*K + g4*8;
  const ush* gB1 = gB0 + (size_t)16*K;
  int fs = (quad ^ (lr & 3)) * 8;

  async16(&smem[(16*w)*32], gA0);
  async16(&smem[4096 + (32*w)*32], gB0);
  async16(&smem[4096 + (32*w+16)*32], gB1);

  for (int kk = 0; kk < K; kk += 32) {
    int cur = (kk >> 5) & 1;
    __syncthreads();
    if (kk + 32 < K) {
      int nx = cur ^ 1;
      async16(&smem[nx*2048 + (16*w)*32], gA0 + kk + 32);
      async16(&smem[4096 + nx*4096 + (32*w)*32], gB0 + kk + 32);
      async16(&smem[4096 + nx*4096 + (32*w+16)*32], gB1 + kk + 32);
    }
    bf16v8 af[2], bfr[4];
#pragma unroll
    for (int j = 0; j < 2; ++j)
      af[j] = *(bf16v8*)&smem[cur*2048 + (wm + j*16 + lr)*32 + fs];
#pragma unroll
    for (int i = 0; i < 4; ++i)
      bfr[i] = *(bf16v8*)&smem[4096 + cur*4096 + (wn + i*16 + lr)*32 + fs];
#pragma unroll
    for (int i = 0; i < 4; ++i)
#pragma unroll
      for (int j = 0; j < 2; ++j)
        acc[i][j] = __builtin_amdgcn_mfma_f32_16x16x32_bf16(bfr[i], af[j],
                                                            acc[i][j], 0, 0, 0);
  }

  int f32out = (flag != nullptr) && (*flag == 0);
  if (f32out) {
    float* Cf = (float*)Cp;
#pragma unroll
    for (int i = 0; i < 4; ++i) {
      int nb = n0 + wn + i*16 + quad*4;
#pragma unroll
      for (int j = 0; j < 2; ++j) {
        int row = m0 + wm + j*16 + lr;
        *(floatv4*)&Cf[(size_t)row*ldc + nb] = acc[i][j];
      }
    }
  } else {
    __hip_bfloat16* Cb = (__hip_bfloat16*)Cp;
#pragma unroll
    for (int i = 0; i < 4; ++i) {
      int nb = n0 + wn + i*16 + quad*4;
#pragma unroll
      for (int j = 0; j < 2; ++j) {
        int row = m0 + wm + j*16 + lr;
        shortv4 v4;
#pragma unroll
        for (int r = 0; r < 4; ++r) v4[r] = (short)f2b(acc[i][j][r]);
        *(shortv4*)&((ush*)Cb)[(size_t)row*ldc + nb] = v4;
      }
    }
  }
}

// ===========================================================================
// Flash attention v14: v12 machinery + SPLIT-K for long q-blocks.
// Our softmax is unnormalized exp2 accumulation (Q pre-scaled, no running
// max), so K-range partials are EXACTLY additive: acc/acl just sum.
// Pieces per head (24): pid 0..15 = split halves of g=8..15 (K-ranges
// [0,g+1) and [g+1,2g+2), each g+1 <= 16 tiles, partials -> pacc/pacl);
// pid 16..23 = unsplit g=7..0 (direct ctx write). Grid 768 = 3 blocks/CU
// (LDS 50KB x 3 = 150KB) -> 24 waves/CU, max block length 32 -> 16 units.
// attn_combine sums split pairs, normalizes, writes ctx.
// ===========================================================================
#define PSTR 72

__device__ __forceinline__ void softpack(const floatv4* s, int qw, int kb0,
                                         bool diag, ush* PsW, int quad, int lr) {
  if (diag) {
#pragma unroll
    for (int r = 0; r < 4; ++r) {
      int qv = qw + quad*4 + r;
      shortv4 p4;
#pragma unroll
      for (int j = 0; j < 4; ++j) {
        float z = (kb0 + 16*j + lr > qv) ? NEG_BIG : s[j][r];
        p4[j] = (short)f2b(__builtin_amdgcn_exp2f(z));
      }
      *(shortv4*)&PsW[(quad*4 + r)*PSTR + lr*4] = p4;
    }
  } else {
#pragma unroll
    for (int r = 0; r < 4; ++r) {
      shortv4 p4;
#pragma unroll
      for (int j = 0; j < 4; ++j)
        p4[j] = (short)f2b(__builtin_amdgcn_exp2f(s[j][r]));
      *(shortv4*)&PsW[(quad*4 + r)*PSTR + lr*4] = p4;
    }
  }
}

__global__ __launch_bounds__(512, 6)
void attn_fwd(const ush* __restrict__ qb_, const ush* __restrict__ kb_,
              const ush* __restrict__ vb_, __hip_bfloat16* __restrict__ ctx,
              float* __restrict__ pacc, float* __restrict__ pacl) {
  __shared__ __align__(16) ush Ks[2][64*64];
  __shared__ __align__(16) ush Vt[2][64*64];
  __shared__ __align__(16) ush Ps[8][16*PSTR];

  int raw = blockIdx.x;
  int bid = (raw & 7) * 96 + (raw >> 3);   // XCD-chunked (768 = 8 x 96): 4 heads/XCD
  int bh  = bid / 24;              // 0..31
  int pid = bid % 24;
  int h   = bh & 15;
  int b   = bh >> 4;

  int g, t0, t1, half; bool split;
  if (pid < 16) {                  // split halves of g = 8..15
    int j = pid >> 1;
    g = 8 + j; half = pid & 1; split = true;
    t0 = half ? (g + 1) : 0;
    t1 = half ? (2*g + 2) : (g + 1);
  } else {                         // unsplit g = 7..0 (heavier first)
    g = 23 - pid; half = 0; split = false;
    t0 = 0; t1 = 2*g + 2;
  }

  int t = threadIdx.x, w8 = t >> 6, lane = t & 63, lr = lane & 15, quad = lane >> 4;

  const ush* qh = qb_ + (size_t)bh * SEQ * 64;
  const ush* kh = kb_ + (size_t)bh * SEQ * 64;
  const ush* vh = vb_ + (size_t)bh * 64 * SEQ;

  int qw     = g*128 + w8*16;
  int myLast = 2*g + (w8 >> 2);
  int wj     = w8 & 3;

  const ush* qp = qh + (size_t)(qw + lr)*64;
  bf16v8 qf0 = *(const bf16v8*)&qp[quad*8];
  bf16v8 qf1 = *(const bf16v8*)&qp[32 + quad*8];

  floatv4 acc[4] = {}, acl = {};

  bf16v8 ones;
#pragma unroll
  for (int j = 0; j < 8; ++j) ones[j] = (__bf16)1.0f;

  int r8 = lane >> 3;
  int s8 = lane & 7;
  int g8 = s8 ^ r8;
  const ush* kg = kh + (size_t)(8*w8 + r8)*64 + g8*8;
  const ush* vg = vh + (size_t)(8*w8 + r8)*SEQ + g8*8;
  int lo = (8*w8)*64;

  int sl0 = quad ^ (lr & 7);
  int sl1 = (quad + 4) ^ (lr & 7);

  async16(&Ks[0][lo], kg + (size_t)t0 * 4096);
  async16(&Vt[0][lo], vg + (size_t)t0 * 64);

  for (int tk = t0; tk < t1; ++tk) {
    int cur = (tk - t0) & 1;
    __syncthreads();
    if (tk + 1 < t1) {
      int nx = cur ^ 1;
      async16(&Ks[nx][lo], kg + (size_t)(tk + 1) * 4096);
      async16(&Vt[nx][lo], vg + (size_t)(tk + 1) * 64);
    }

    bool live = (tk <= myLast);
    if (live) {
      int kb0 = tk * 64;
      bool diag = (tk == myLast);

      floatv4 s[4] = {};
      __builtin_amdgcn_s_setprio(1);
#pragma unroll
      for (int j = 0; j < 4; ++j) {
        if (!diag || j <= wj) {
          int row = 16*j + lr;
          bf16v8 kf0 = *(bf16v8*)&Ks[cur][row*64 + sl0*8];
          bf16v8 kf1 = *(bf16v8*)&Ks[cur][row*64 + sl1*8];
          s[j] = MFMA16(qf0, kf0, s[j]);
          s[j] = MFMA16(qf1, kf1, s[j]);
        }
      }
      __builtin_amdgcn_s_setprio(0);

      softpack(s, qw, kb0, diag, &Ps[w8][0], quad, lr);

      bf16v8 pf0 = *(bf16v8*)&Ps[w8][lr*PSTR + quad*8];
      bf16v8 pf1 = *(bf16v8*)&Ps[w8][lr*PSTR + 32 + quad*8];

      __builtin_amdgcn_s_setprio(1);
      acl = MFMA16(pf0, ones, acl);
      acl = MFMA16(pf1, ones, acl);

#pragma unroll
      for (int c = 0; c < 4; ++c) {
        int row = 16*c + lr;
        bf16v8 vf0 = *(bf16v8*)&Vt[cur][row*64 + sl0*8];
        bf16v8 vf1 = *(bf16v8*)&Vt[cur][row*64 + sl1*8];
        acc[c] = MFMA16(pf0, vf0, acc[c]);
        acc[c] = MFMA16(pf1, vf1, acc[c]);
      }
      __builtin_amdgcn_s_setprio(0);
    }
  }

  if (!split) {
#pragma unroll
    for (int r = 0; r < 4; ++r) {
      float inv = 1.0f / fmaxf(acl[r], 1e-30f);
      size_t o = (size_t)(b*SEQ + qw + quad*4 + r) * D_MODEL + h*64;
#pragma unroll
      for (int c = 0; c < 4; ++c)
        ctx[o + c*16 + lr] = __float2bfloat16(acc[c][r] * inv);
    }
  } else {
    // partial write: slot = (bh*8 + (g-8))*2 + half; layout [128][64] f32
    int slot = (bh*8 + (g - 8))*2 + half;
    float* pa = pacc + (size_t)slot * 8192;
#pragma unroll
    for (int r = 0; r < 4; ++r) {
      int row = w8*16 + quad*4 + r;
#pragma unroll
      for (int c = 0; c < 4; ++c)
        pa[row*64 + c*16 + lr] = acc[c][r];
    }
    if (lr == 0) {
#pragma unroll
      for (int r = 0; r < 4; ++r)
        pacl[(size_t)slot*128 + w8*16 + quad*4 + r] = acl[r];
    }
  }
}

// ---------------------------------------------------------------------------
// Combine split-K partials: sum pair, normalize, write bf16 ctx.
// Grid 256 (= 32 bh x 8 j), 256 threads; thread -> (row = t>>1, 32 cols).
// ---------------------------------------------------------------------------
__global__ __launch_bounds__(256)
void attn_combine(const float* __restrict__ pacc, const float* __restrict__ pacl,
                  __hip_bfloat16* __restrict__ ctx) {
  int blk = blockIdx.x;            // bh*8 + j
  int bh  = blk >> 3, j = blk & 7;
  int g   = 8 + j;
  int h   = bh & 15, b = bh >> 4;
  int t   = threadIdx.x;
  int row = t >> 1;
  int c0  = (t & 1) * 32;

  const float* a0 = pacc + (size_t)blk * 2 * 8192 + row*64;
  const float* a1 = a0 + 8192;
  float l = pacl[(size_t)blk*2*128 + row] + pacl[(size_t)blk*2*128 + 128 + row];
  float inv = 1.0f / fmaxf(l, 1e-30f);
  size_t o = (size_t)(b*SEQ + g*128 + row) * D_MODEL + h*64 + c0;

#pragma unroll
  for (int cc = 0; cc < 32; cc += 4) {
    floatv4 x0 = *(const floatv4*)&a0[c0 + cc];
    floatv4 x1 = *(const floatv4*)&a1[c0 + cc];
    shortv4 v4;
#pragma unroll
    for (int r = 0; r < 4; ++r) v4[r] = (short)f2b((x0[r] + x1[r]) * inv);
    *(shortv4*)&((ush*)ctx)[o + cc] = v4;
  }
}

// ---------------------------------------------------------------------------
extern "C" void kernel_launch(void* const* d_in, const int* in_sizes, int n_in,
                              void* d_out, int out_size, void* d_ws, size_t ws_size,
                              hipStream_t stream) {
  const void* x      = d_in[0];
  const void* w_qkv  = d_in[1];
  const void* w_proj = d_in[2];

  int* flag   = (int*)d_ws;
  ush* xb     = (ush*)d_ws + 8;
  ush* wqkvT  = xb     + (size_t)ROWS * D_MODEL;
  ush* wprojT = wqkvT  + (size_t)3072 * 1024;
  ush* qbuf   = wprojT + (size_t)1024 * 1024;
  ush* kbuf   = qbuf   + (size_t)32 * SEQ * 64;
  ush* vbuf   = kbuf   + (size_t)32 * SEQ * 64;
  float* pacc = (float*)(vbuf + (size_t)32 * SEQ * 64);   // 512 x 8192 f32
  float* pacl = pacc + (size_t)512 * 8192;                // 512 x 128 f32
  ush* ctx    = xb;   // alias: xb dead after gemm_qkv, before attn writes ctx

  prep<<<3072, 256, 0, stream>>>((const uint32_t*)x, xb,
                                 w_qkv, wqkvT, w_proj, wprojT, flag);

  gemm_qkv<<<192, 512, 0, stream>>>(xb, wqkvT, qbuf, kbuf, vbuf);

  // split-K attention: 32 bh x 24 pieces = 768 blocks, 3 blocks/CU
  attn_fwd<<<768, 512, 0, stream>>>(
      qbuf, kbuf, vbuf, (__hip_bfloat16*)ctx, pacc, pacl);

  attn_combine<<<256, 256, 0, stream>>>(pacc, pacl, (__hip_bfloat16*)ctx);

  gemm_bt<<<(ROWS/64)*(1024/128), 256, 0, stream>>>(
      ctx, wprojT, d_out, flag, 1024, 1024/128);
}